// Round 8
// baseline (49.404 us; speedup 1.0000x reference)
//
#include <hip/hip_runtime.h>
#include <math.h>

// HAKE scoring for MI355X — round 8: kill the transcendental pipe.
// R7 lesson: VALUBusy*dur ~= 21.7us matches v_sin at ~16cyc/wave64 -> kernel
// is trans-issue-bound; occupancy 33->47% bought nothing. Replace |sin(2*pi*y)|
// with cos(pi*w), w = u - rint(u), u = 2y-0.5 : even poly in w^2, pure
// (packed) FMA, no abs/fract/sin. ~9 issue-cyc/triple vs ~20. Rest = R7.

#define D_   256
#define N_   20000
#define NT   16
#define NBLK (N_ / NT)      // 1250
#define AP   264            // bf16 pitch

// 1/(2*EMB_RANGE): phase diff -> t with |sin(pi*t)| semantics
#define TWOK2S 9.142857142857142f
// cos(pi*w) = 1 + v*(C2 + v*(C4 + v*C6)), v = w^2, |w|<=0.5  (err ~9e-4)
#define C2c (-4.934802200544679f)
#define C4c ( 4.058712126416768f)
#define C6c (-1.3352627688545894f)

typedef short short8 __attribute__((ext_vector_type(8)));
typedef float f32x4  __attribute__((ext_vector_type(4)));
typedef float f32x2  __attribute__((ext_vector_type(2)));

__device__ __forceinline__ short bf16r(float x) {
    union { float f; unsigned u; } v; v.f = x;
    unsigned r = (v.u + 0x7FFFu + ((v.u >> 16) & 1u)) >> 16;
    return (short)r;
}

__device__ __forceinline__ short8 pack8(float4 a, float4 b, bool sq) {
    float v[8] = {a.x, a.y, a.z, a.w, b.x, b.y, b.z, b.w};
    short8 r;
#pragma unroll
    for (int i = 0; i < 8; ++i) { float x = sq ? v[i] * v[i] : v[i]; r[i] = bf16r(x); }
    return r;
}

__global__ __launch_bounds__(512, 6)
void hake_fused(const int* __restrict__ e1, const int* __restrict__ rel,
                const float* __restrict__ emb_e, const float* __restrict__ emb_rel,
                const float* __restrict__ pw_p, const float* __restrict__ mw_p,
                float* __restrict__ out)
{
    __shared__ short A1[32 * AP];        // cc^2        16.9 KB
    __shared__ short A2[32 * AP];        // -2*mh'*cc   16.9 KB
    __shared__ float U[4352];            // 17.4 KB union: redr[8][32][17] | P[16][64]f4 | redf[8][16][32]
    __shared__ float S0p[16][32];        // 2 KB
    __shared__ float S0[32];

    const int t  = threadIdx.x;
    const int l  = t & 63;
    const int w  = t >> 6;        // wave 0..7
    const int b  = t & 31;
    const int g  = t >> 5;        // d-group 0..15 (16 d each)
    const int d0 = g * 16;
    const int fr = l & 15;
    const int hi = l >> 4;
    const int n0 = blockIdx.x * NT;

    // ---- B prefetch: wave w -> term (w>>2), d-slice (w&3)*64 ---------------
    const int term  = w >> 2;
    const int dbase = (w & 3) * 64;
    const float* mtp = emb_e + (size_t)(n0 + fr) * (2 * D_) + D_;
    float4 bva0 = *(const float4*)(mtp + dbase + hi * 8);
    float4 bvb0 = *(const float4*)(mtp + dbase + hi * 8 + 4);
    float4 bva1 = *(const float4*)(mtp + dbase + 32 + hi * 8);
    float4 bvb1 = *(const float4*)(mtp + dbase + 32 + hi * 8 + 4);

    // ---- P loads into regs (LDS write deferred past r-reduce) --------------
    const float* prow0 = emb_e + (size_t)(n0 + w * 2) * (2 * D_);
    const float* prow1 = emb_e + (size_t)(n0 + w * 2 + 1) * (2 * D_);
    float4 pv0 = *(const float4*)(prow0 + l * 4);
    float4 pv1 = *(const float4*)(prow1 + l * 4);

    // ---- head/rel tables: arS pairs (regs), A1/A2 (LDS), S0 partial --------
    f32x2 arP[8];     // arS[i] = (ph+pr)*TWOK2S - 0.5, packed by d-pair
    {
        const int he = e1[b], hr = rel[b];
        const float* be = emb_e  + (size_t)he * (2 * D_);
        const float* br = emb_rel + (size_t)hr * (3 * D_);
        float a1v[16], a2v[16];
        float s0 = 0.0f;
#pragma unroll
        for (int q = 0; q < 4; ++q) {
            float4 ph4 = *(const float4*)(be + d0 + q * 4);
            float4 pq4 = *(const float4*)(br + d0 + q * 4);
            float4 mh4 = *(const float4*)(be + D_ + d0 + q * 4);
            float4 mr4 = *(const float4*)(br + D_ + d0 + q * 4);
            float4 bi4 = *(const float4*)(br + 2 * D_ + d0 + q * 4);
            float phv[4] = {ph4.x, ph4.y, ph4.z, ph4.w};
            float pqv[4] = {pq4.x, pq4.y, pq4.z, pq4.w};
            float mhv[4] = {mh4.x, mh4.y, mh4.z, mh4.w};
            float mrv[4] = {mr4.x, mr4.y, mr4.z, mr4.w};
            float biv[4] = {bi4.x, bi4.y, bi4.z, bi4.w};
#pragma unroll
            for (int k = 0; k < 4; ++k) {
                const int i = q * 4 + k;
                arP[i >> 1][i & 1] = (phv[k] + pqv[k]) * TWOK2S - 0.5f;
                float mr = fabsf(mrv[k]);
                float bi = fminf(biv[k], 1.0f);
                bi = (bi < -mr) ? -mr : bi;
                float cc = 1.0f - bi;
                float mh = mhv[k] * (mr + bi);
                a1v[i] = cc * cc;
                a2v[i] = -2.0f * mh * cc;
                s0 = fmaf(mh, mh, s0);
            }
        }
        short8 w1a, w1b, w2a, w2b;
#pragma unroll
        for (int i = 0; i < 8; ++i) {
            w1a[i] = bf16r(a1v[i]);     w1b[i] = bf16r(a1v[8 + i]);
            w2a[i] = bf16r(a2v[i]);     w2b[i] = bf16r(a2v[8 + i]);
        }
        *(short8*)(&A1[b * AP + d0])     = w1a;
        *(short8*)(&A1[b * AP + d0 + 8]) = w1b;
        *(short8*)(&A2[b * AP + d0])     = w2a;
        *(short8*)(&A2[b * AP + d0 + 8]) = w2b;
        S0p[g][b] = s0;
    }
    __syncthreads();                                    // b1: A + S0p ready

    if (t < 32) {
        float s = 0.0f;
#pragma unroll
        for (int q = 0; q < 16; ++q) s += S0p[q][t];
        S0[t] = s;
    }

    // ---- r-term MFMAs: 2 m-tiles x 2 k-steps per wave; partials -> U -------
    {
        short8 bf0 = pack8(bva0, bvb0, term == 0);
        short8 bf1 = pack8(bva1, bvb1, term == 0);
        const short* At = term ? A2 : A1;
        short8 a00 = *(const short8*)(At + fr * AP + dbase + hi * 8);
        short8 a01 = *(const short8*)(At + fr * AP + dbase + 32 + hi * 8);
        short8 a10 = *(const short8*)(At + (16 + fr) * AP + dbase + hi * 8);
        short8 a11 = *(const short8*)(At + (16 + fr) * AP + dbase + 32 + hi * 8);
        f32x4 acc0 = {0.f, 0.f, 0.f, 0.f};
        f32x4 acc1 = {0.f, 0.f, 0.f, 0.f};
        acc0 = __builtin_amdgcn_mfma_f32_16x16x32_bf16(a00, bf0, acc0, 0, 0, 0);
        acc0 = __builtin_amdgcn_mfma_f32_16x16x32_bf16(a01, bf1, acc0, 0, 0, 0);
        acc1 = __builtin_amdgcn_mfma_f32_16x16x32_bf16(a10, bf0, acc1, 0, 0, 0);
        acc1 = __builtin_amdgcn_mfma_f32_16x16x32_bf16(a11, bf1, acc1, 0, 0, 0);
        // C/D map (verified): col = lane&15 (n), row = hi*4 + reg (b)
#pragma unroll
        for (int r = 0; r < 4; ++r) {
            U[(w * 32 + hi * 4 + r) * 17 + fr]      = acc0[r];
            U[(w * 32 + 16 + hi * 4 + r) * 17 + fr] = acc1[r];
        }
    }
    __syncthreads();                                    // b3: redr ready

    // ---- r reduce: thread t -> (b = t&31, n = t>>5) ------------------------
    const int fn = t >> 5, fb = t & 31;
    float rr = 0.0f;
#pragma unroll
    for (int ww = 0; ww < 8; ++ww) rr += U[(ww * 32 + fb) * 17 + fn];
    __syncthreads();                                    // b4: redr consumed

    // ---- P -> LDS (union region): pt2 = pt * TWOK2S ------------------------
    float4* Pp = (float4*)U;                            // P[16][64] float4
    Pp[(w * 2) * 64 + l]     = make_float4(pv0.x * TWOK2S, pv0.y * TWOK2S,
                                           pv0.z * TWOK2S, pv0.w * TWOK2S);
    Pp[(w * 2 + 1) * 64 + l] = make_float4(pv1.x * TWOK2S, pv1.y * TWOK2S,
                                           pv1.z * TWOK2S, pv1.w * TWOK2S);
    __syncthreads();                                    // b5: P ready

    // ---- phase accumulate: 16 d x 16 n per thread, packed poly -------------
    f32x2 acc[NT];
#pragma unroll
    for (int j = 0; j < NT; ++j) acc[j] = (f32x2){0.0f, 0.0f};

    const f32x2 vC6 = {C6c, C6c}, vC4 = {C4c, C4c}, vC2 = {C2c, C2c};
    const f32x2 v1  = {1.0f, 1.0f};
#pragma unroll
    for (int q = 0; q < 4; ++q) {
#pragma unroll
        for (int j = 0; j < NT; ++j) {
            float4 tv = Pp[j * 64 + g * 4 + q];         // broadcast in 32-lane group
            const f32x2* tp = (const f32x2*)&tv;
#pragma unroll
            for (int h2 = 0; h2 < 2; ++h2) {
                f32x2 tt = arP[q * 2 + h2] - tp[h2];    // u = arS - pt2
                f32x2 rr2; rr2.x = __builtin_rintf(tt.x); rr2.y = __builtin_rintf(tt.y);
                f32x2 ww = tt - rr2;                    // w in [-0.5, 0.5]
                f32x2 vv = ww * ww;
                f32x2 pp = __builtin_elementwise_fma(vv, vC6, vC4);
                pp = __builtin_elementwise_fma(vv, pp, vC2);
                pp = __builtin_elementwise_fma(vv, pp, v1);   // cos(pi*w) = |sin|
                acc[j] += pp;
            }
        }
    }

    // ---- phase reduce ------------------------------------------------------
    float sph[NT];
#pragma unroll
    for (int j = 0; j < NT; ++j) sph[j] = acc[j].x + acc[j].y;
#pragma unroll
    for (int j = 0; j < NT; ++j) sph[j] += __shfl_xor(sph[j], 32, 64);
    __syncthreads();                                    // b6: P consumed
    if (l < 32) {
#pragma unroll
        for (int j = 0; j < NT; ++j) U[(w * 16 + j) * 32 + l] = sph[j];
    }
    __syncthreads();                                    // b7: redf ready

    // ---- finalize: thread t -> (b = fb, n = n0 + fn) -----------------------
    {
        float pa = 0.0f;
#pragma unroll
        for (int ww = 0; ww < 8; ++ww) pa += U[(ww * 16 + fn) * 32 + fb];
        float rfull = fmaxf(rr + S0[fb], 0.0f);
        float z = fmaf(pa, pw_p[0], sqrtf(rfull) * mw_p[0]) - 12.0f;  // GAMMA
        out[(size_t)fb * N_ + (n0 + fn)] = 1.0f / (1.0f + __expf(z));
    }
}

extern "C" void kernel_launch(void* const* d_in, const int* in_sizes, int n_in,
                              void* d_out, int out_size, void* d_ws, size_t ws_size,
                              hipStream_t stream)
{
    // inputs: 0:g 1:e1 2:rel 3:e2_multi(unused) 4:emb_e 5:emb_rel 6:phase_w 7:mod_w
    const int*   e1      = (const int*)d_in[1];
    const int*   rel     = (const int*)d_in[2];
    const float* emb_e   = (const float*)d_in[4];
    const float* emb_rel = (const float*)d_in[5];
    const float* pw      = (const float*)d_in[6];
    const float* mw      = (const float*)d_in[7];
    float* out = (float*)d_out;

    hipLaunchKernelGGL(hake_fused, dim3(NBLK), dim3(512), 0, stream,
                       e1, rel, emb_e, emb_rel, pw, mw, out);
}

// Round 9
// 40.740 us; speedup vs baseline: 1.2126x; 1.2126x over previous
//
#include <hip/hip_runtime.h>
#include <math.h>

// HAKE scoring for MI355X — round 9: angle-addition restructure.
// R8 lesson: f32x2 "packed" poly spilled to scratch (WRITE 10MB) and
// scalarized — revert. Instead kill range-reduction: |sin(a-b)| =
// |sin a cos b - cos a sin b|; sin/cos precomputed (a: per b,d table;
// b: per n,d staged — each tail row belongs to exactly one block).
// Inner loop: mul + fma + add|abs| = 3 VALU/triple, no trans/fract/rint.
// P=(sb,cb) f32 pairs (32KB) overlays dead A1/A2 region after MFMAs.
// LDS 53.4KB -> 3 blocks/CU.

#define D_   256
#define N_   20000
#define NT   16
#define NBLK (N_ / NT)      // 1250
#define AP   264            // bf16 pitch for A tables

// rev units for sin(x/2), x in "radians*scale": 1/(4*EMB_RANGE)
#define K2S 4.571428571428571f

typedef short short8 __attribute__((ext_vector_type(8)));
typedef float f32x4  __attribute__((ext_vector_type(4)));

__device__ __forceinline__ float sinrev_(float x) { return __builtin_amdgcn_sinf(x); }
__device__ __forceinline__ float cosrev_(float x) { return __builtin_amdgcn_cosf(x); }

__device__ __forceinline__ short bf16r(float x) {
    union { float f; unsigned u; } v; v.f = x;
    unsigned r = (v.u + 0x7FFFu + ((v.u >> 16) & 1u)) >> 16;
    return (short)r;
}

__device__ __forceinline__ short8 pack8(float4 a, float4 b, bool sq) {
    float v[8] = {a.x, a.y, a.z, a.w, b.x, b.y, b.z, b.w};
    short8 r;
#pragma unroll
    for (int i = 0; i < 8; ++i) { float x = sq ? v[i] * v[i] : v[i]; r[i] = bf16r(x); }
    return r;
}

__global__ __launch_bounds__(512, 6)
void hake_fused(const int* __restrict__ e1, const int* __restrict__ rel,
                const float* __restrict__ emb_e, const float* __restrict__ emb_rel,
                const float* __restrict__ pw_p, const float* __restrict__ mw_p,
                float* __restrict__ out)
{
    // A1[32*AP], A2[32*AP] (bf16, 33.8KB); after b4 reused as Ps[16][128] float4
    __shared__ __align__(16) char ABP[2 * 32 * AP * 2];
    __shared__ float U[4352];            // redr[8][32][17] | redf[8][16][32]
    __shared__ float S0p[16][32];
    __shared__ float S0[32];

    short* A1 = (short*)ABP;
    short* A2 = (short*)(ABP + 32 * AP * 2);

    const int t  = threadIdx.x;
    const int l  = t & 63;
    const int w  = t >> 6;        // wave 0..7
    const int b  = t & 31;
    const int g  = t >> 5;        // d-group 0..15 (16 d each)
    const int d0 = g * 16;
    const int fr = l & 15;
    const int hi = l >> 4;
    const int n0 = blockIdx.x * NT;

    // ---- B prefetch: wave w -> term (w>>2), d-slice (w&3)*64 ---------------
    const int term  = w >> 2;
    const int dbase = (w & 3) * 64;
    const float* mtp = emb_e + (size_t)(n0 + fr) * (2 * D_) + D_;
    float4 bva0 = *(const float4*)(mtp + dbase + hi * 8);
    float4 bvb0 = *(const float4*)(mtp + dbase + hi * 8 + 4);
    float4 bva1 = *(const float4*)(mtp + dbase + 32 + hi * 8);
    float4 bvb1 = *(const float4*)(mtp + dbase + 32 + hi * 8 + 4);

    // ---- phase-row loads: rows 2w,2w+1; half h -> d = 128h + 2l ------------
    const float* prow0 = emb_e + (size_t)(n0 + w * 2) * (2 * D_);
    const float* prow1 = emb_e + (size_t)(n0 + w * 2 + 1) * (2 * D_);
    float2 lp00 = *(const float2*)(prow0 + 2 * l);
    float2 lp01 = *(const float2*)(prow0 + 128 + 2 * l);
    float2 lp10 = *(const float2*)(prow1 + 2 * l);
    float2 lp11 = *(const float2*)(prow1 + 128 + 2 * l);

    const int he = e1[b], hr = rel[b];
    const float* be = emb_e  + (size_t)he * (2 * D_);
    const float* br = emb_rel + (size_t)hr * (3 * D_);

    // ---- A tables (mod part only) + S0 partial -----------------------------
    {
        float a1v[16], a2v[16];
        float s0 = 0.0f;
#pragma unroll
        for (int q = 0; q < 4; ++q) {
            float4 mh4 = *(const float4*)(be + D_ + d0 + q * 4);
            float4 mr4 = *(const float4*)(br + D_ + d0 + q * 4);
            float4 bi4 = *(const float4*)(br + 2 * D_ + d0 + q * 4);
            float mhv[4] = {mh4.x, mh4.y, mh4.z, mh4.w};
            float mrv[4] = {mr4.x, mr4.y, mr4.z, mr4.w};
            float biv[4] = {bi4.x, bi4.y, bi4.z, bi4.w};
#pragma unroll
            for (int k = 0; k < 4; ++k) {
                const int i = q * 4 + k;
                float mr = fabsf(mrv[k]);
                float bi = fminf(biv[k], 1.0f);
                bi = (bi < -mr) ? -mr : bi;
                float cc = 1.0f - bi;
                float mh = mhv[k] * (mr + bi);
                a1v[i] = cc * cc;
                a2v[i] = -2.0f * mh * cc;
                s0 = fmaf(mh, mh, s0);
            }
        }
        short8 w1a, w1b, w2a, w2b;
#pragma unroll
        for (int i = 0; i < 8; ++i) {
            w1a[i] = bf16r(a1v[i]);     w1b[i] = bf16r(a1v[8 + i]);
            w2a[i] = bf16r(a2v[i]);     w2b[i] = bf16r(a2v[8 + i]);
        }
        *(short8*)(&A1[b * AP + d0])     = w1a;
        *(short8*)(&A1[b * AP + d0 + 8]) = w1b;
        *(short8*)(&A2[b * AP + d0])     = w2a;
        *(short8*)(&A2[b * AP + d0 + 8]) = w2b;
        S0p[g][b] = s0;
    }
    __syncthreads();                                    // b1: A + S0p ready

    if (t < 32) {
        float s = 0.0f;
#pragma unroll
        for (int q = 0; q < 16; ++q) s += S0p[q][t];
        S0[t] = s;
    }

    // ---- r-term MFMAs: 2 m-tiles x 2 k-steps per wave; partials -> U -------
    {
        short8 bf0 = pack8(bva0, bvb0, term == 0);
        short8 bf1 = pack8(bva1, bvb1, term == 0);
        const short* At = term ? A2 : A1;
        short8 a00 = *(const short8*)(At + fr * AP + dbase + hi * 8);
        short8 a01 = *(const short8*)(At + fr * AP + dbase + 32 + hi * 8);
        short8 a10 = *(const short8*)(At + (16 + fr) * AP + dbase + hi * 8);
        short8 a11 = *(const short8*)(At + (16 + fr) * AP + dbase + 32 + hi * 8);
        f32x4 acc0 = {0.f, 0.f, 0.f, 0.f};
        f32x4 acc1 = {0.f, 0.f, 0.f, 0.f};
        acc0 = __builtin_amdgcn_mfma_f32_16x16x32_bf16(a00, bf0, acc0, 0, 0, 0);
        acc0 = __builtin_amdgcn_mfma_f32_16x16x32_bf16(a01, bf1, acc0, 0, 0, 0);
        acc1 = __builtin_amdgcn_mfma_f32_16x16x32_bf16(a10, bf0, acc1, 0, 0, 0);
        acc1 = __builtin_amdgcn_mfma_f32_16x16x32_bf16(a11, bf1, acc1, 0, 0, 0);
        // C/D map (verified): col = lane&15 (n), row = hi*4 + reg (b)
#pragma unroll
        for (int r = 0; r < 4; ++r) {
            U[(w * 32 + hi * 4 + r) * 17 + fr]      = acc0[r];
            U[(w * 32 + 16 + hi * 4 + r) * 17 + fr] = acc1[r];
        }
    }
    __syncthreads();                                    // b3: redr ready

    // ---- r reduce: thread t -> (b = t&31, n = t>>5) ------------------------
    const int fn = t >> 5, fb = t & 31;
    float rr = 0.0f;
#pragma unroll
    for (int ww = 0; ww < 8; ++ww) rr += U[(ww * 32 + fb) * 17 + fn];
    __syncthreads();                                    // b4: redr + A consumed

    // ---- sa/ca head table (after b4 to cut peak VGPR; rows are L2-hot) -----
    float sa[16], ca[16];
#pragma unroll
    for (int q = 0; q < 4; ++q) {
        float4 ph4 = *(const float4*)(be + d0 + q * 4);
        float4 pq4 = *(const float4*)(br + d0 + q * 4);
        float av[4] = {(ph4.x + pq4.x) * K2S, (ph4.y + pq4.y) * K2S,
                       (ph4.z + pq4.z) * K2S, (ph4.w + pq4.w) * K2S};
#pragma unroll
        for (int k = 0; k < 4; ++k) {
            sa[q * 4 + k] = sinrev_(av[k]);
            ca[q * 4 + k] = cosrev_(av[k]);
        }
    }

    // ---- P = (sinb, cosb) pairs into old A region --------------------------
    float4* Pf = (float4*)ABP;          // Ps[16][128] float4: row*128 + pair
    {
        float2 lps[4] = {lp00, lp01, lp10, lp11};
#pragma unroll
        for (int r2 = 0; r2 < 2; ++r2) {
#pragma unroll
            for (int h = 0; h < 2; ++h) {
                float2 lp = lps[r2 * 2 + h];
                float b0 = lp.x * K2S, b1 = lp.y * K2S;
                Pf[(w * 2 + r2) * 128 + h * 64 + l] =
                    make_float4(sinrev_(b0), cosrev_(b0), sinrev_(b1), cosrev_(b1));
            }
        }
    }
    __syncthreads();                                    // b5: P ready

    // ---- phase accumulate: 16 d x 16 n per thread, 3 VALU/triple -----------
    float sph[NT];
#pragma unroll
    for (int j = 0; j < NT; ++j) sph[j] = 0.0f;

#pragma unroll
    for (int dd = 0; dd < 8; ++dd) {
#pragma unroll
        for (int j = 0; j < NT; ++j) {
            float4 tv = Pf[j * 128 + g * 8 + dd];       // (sb0,cb0,sb1,cb1) bcast
            float s0 = fmaf(-ca[2 * dd],     tv.x, sa[2 * dd]     * tv.y);
            float s1 = fmaf(-ca[2 * dd + 1], tv.z, sa[2 * dd + 1] * tv.w);
            sph[j] += fabsf(s0);
            sph[j] += fabsf(s1);
        }
    }

    // ---- phase reduce ------------------------------------------------------
#pragma unroll
    for (int j = 0; j < NT; ++j) sph[j] += __shfl_xor(sph[j], 32, 64);
    if (l < 32) {
#pragma unroll
        for (int j = 0; j < NT; ++j) U[(w * 16 + j) * 32 + l] = sph[j];
    }
    __syncthreads();                                    // b7: redf ready

    // ---- finalize: thread t -> (b = fb, n = n0 + fn) -----------------------
    {
        float pa = 0.0f;
#pragma unroll
        for (int ww = 0; ww < 8; ++ww) pa += U[(ww * 16 + fn) * 32 + fb];
        float rfull = fmaxf(rr + S0[fb], 0.0f);
        float z = fmaf(pa, pw_p[0], sqrtf(rfull) * mw_p[0]) - 12.0f;  // GAMMA
        out[(size_t)fb * N_ + (n0 + fn)] = 1.0f / (1.0f + __expf(z));
    }
}

extern "C" void kernel_launch(void* const* d_in, const int* in_sizes, int n_in,
                              void* d_out, int out_size, void* d_ws, size_t ws_size,
                              hipStream_t stream)
{
    // inputs: 0:g 1:e1 2:rel 3:e2_multi(unused) 4:emb_e 5:emb_rel 6:phase_w 7:mod_w
    const int*   e1      = (const int*)d_in[1];
    const int*   rel     = (const int*)d_in[2];
    const float* emb_e   = (const float*)d_in[4];
    const float* emb_rel = (const float*)d_in[5];
    const float* pw      = (const float*)d_in[6];
    const float* mw      = (const float*)d_in[7];
    float* out = (float*)d_out;

    hipLaunchKernelGGL(hake_fused, dim3(NBLK), dim3(512), 0, stream,
                       e1, rel, emb_e, emb_rel, pw, mw, out);
}

// Round 10
// 34.382 us; speedup vs baseline: 1.4369x; 1.1849x over previous
//
#include <hip/hip_runtime.h>
#include <math.h>

// HAKE scoring for MI355X — round 10: LDS-instruction diet + prep kernel.
// R9 lesson: wall = LDS pipe (per-CU 85B/cyc): 128 b128 reads/wave ~ 25us/CU.
// R7 (64 reads, v_sin) and R9 (128 reads, 3-VALU) hit the same 42us from
// opposite pipes. Fix: (1) pack (sinb,cosb) bf16 into u32 -> 4 triples per
// b128 read -> 64 reads/wave; (2) prep kernel K0 precomputes A1/A2/SC/S0
// into d_ws -> main loses A-build + head trans, 3 barriers, 33.8KB LDS ->
// 4 blocks/CU, VGPR<=64 target.

#define D_   256
#define N_   20000
#define NT   16
#define NBLK (N_ / NT)      // 1250

// rev units for sin(x/2): 1/(4*EMB_RANGE)
#define K2S 4.571428571428571f

// ws layout (bytes)
#define WS_A1 0
#define WS_A2 16384
#define WS_SC 32768
#define WS_S0 65536

typedef short short8 __attribute__((ext_vector_type(8)));
typedef float f32x4  __attribute__((ext_vector_type(4)));

__device__ __forceinline__ float sinrev_(float x) { return __builtin_amdgcn_sinf(x); }
__device__ __forceinline__ float cosrev_(float x) { return __builtin_amdgcn_cosf(x); }
__device__ __forceinline__ float asf_(unsigned u) { union { unsigned u; float f; } v; v.u = u; return v.f; }

__device__ __forceinline__ unsigned short bf16r(float x) {
    union { float f; unsigned u; } v; v.f = x;
    return (unsigned short)((v.u + 0x7FFFu + ((v.u >> 16) & 1u)) >> 16);
}

__device__ __forceinline__ short8 pack8(float4 a, float4 b, bool sq) {
    float v[8] = {a.x, a.y, a.z, a.w, b.x, b.y, b.z, b.w};
    short8 r;
#pragma unroll
    for (int i = 0; i < 8; ++i) { float x = sq ? v[i] * v[i] : v[i]; r[i] = (short)bf16r(x); }
    return r;
}

// ---------------------------------------------------------------------------
// K0: per-(b,d) precompute. 32 blocks x 256 thr. Writes A1/A2 (bf16),
// SC (packed bf16 (sa,ca)), S0 into ws.
// ---------------------------------------------------------------------------
__global__ __launch_bounds__(256)
void hake_prep(const int* __restrict__ e1, const int* __restrict__ rel,
               const float* __restrict__ emb_e, const float* __restrict__ emb_rel,
               char* __restrict__ ws)
{
    __shared__ float sp[4];
    const int b = blockIdx.x, d = threadIdx.x;
    const int he = e1[b], hr = rel[b];
    const float ph = emb_e[(size_t)he * 512 + d];
    const float mh = emb_e[(size_t)he * 512 + 256 + d];
    const float pr = emb_rel[(size_t)hr * 768 + d];
    const float mr = emb_rel[(size_t)hr * 768 + 256 + d];
    const float bi = emb_rel[(size_t)hr * 768 + 512 + d];

    const float a = (ph + pr) * K2S;
    ((unsigned*)(ws + WS_SC))[b * 256 + d] =
        ((unsigned)bf16r(cosrev_(a)) << 16) | (unsigned)bf16r(sinrev_(a));

    const float mra = fabsf(mr);
    float bic = fminf(bi, 1.0f);
    bic = (bic < -mra) ? -mra : bic;
    const float cc  = 1.0f - bic;
    const float mhp = mh * (mra + bic);
    ((short*)(ws + WS_A1))[b * 256 + d] = (short)bf16r(cc * cc);
    ((short*)(ws + WS_A2))[b * 256 + d] = (short)bf16r(-2.0f * mhp * cc);

    float s0 = mhp * mhp;
#pragma unroll
    for (int o = 1; o < 64; o <<= 1) s0 += __shfl_xor(s0, o, 64);
    if ((threadIdx.x & 63) == 0) sp[threadIdx.x >> 6] = s0;
    __syncthreads();
    if (threadIdx.x == 0)
        ((float*)(ws + WS_S0))[b] = sp[0] + sp[1] + sp[2] + sp[3];
}

// ---------------------------------------------------------------------------
// Main: grid 1250 x 512. LDS: Pb (packed bf16 (sb,cb), 16KB) + U (17.4KB).
// Flow: loads -> stage Pb + MFMA partials -> b1 -> r-reduce + inner -> b2 ->
// redf -> b3 -> finalize. 3 barriers.
// ---------------------------------------------------------------------------
__global__ __launch_bounds__(512, 8)
void hake_main(const float* __restrict__ emb_e,
               const char* __restrict__ ws,
               const float* __restrict__ pw_p, const float* __restrict__ mw_p,
               float* __restrict__ out)
{
    __shared__ unsigned Pb[NT * 256];    // 16 KB packed (sb,cb)
    __shared__ float U[4352];            // redr[8][32][17] | redf[8][16][32]

    const int t  = threadIdx.x;
    const int l  = t & 63;
    const int w  = t >> 6;        // wave 0..7
    const int b  = t & 31;
    const int g  = t >> 5;        // d-group 0..15
    const int d0 = g * 16;
    const int fr = l & 15;
    const int hi = l >> 4;
    const int n0 = blockIdx.x * NT;

    const short*    A1w = (const short*)(ws + WS_A1);
    const short*    A2w = (const short*)(ws + WS_A2);
    const unsigned* SCw = (const unsigned*)(ws + WS_SC);
    const float*    S0w = (const float*)(ws + WS_S0);

    // ---- B-frag loads (mod half of 16 tail rows) ---------------------------
    const int term  = w >> 2;
    const int dbase = (w & 3) * 64;
    const float* mtp = emb_e + (size_t)(n0 + fr) * (2 * D_) + D_;
    float4 bva0 = *(const float4*)(mtp + dbase + hi * 8);
    float4 bvb0 = *(const float4*)(mtp + dbase + hi * 8 + 4);
    float4 bva1 = *(const float4*)(mtp + dbase + 32 + hi * 8);
    float4 bvb1 = *(const float4*)(mtp + dbase + 32 + hi * 8 + 4);

    // ---- phase-row loads: rows 2w,2w+1; d = 2l, 128+2l ---------------------
    const float* prow0 = emb_e + (size_t)(n0 + w * 2) * (2 * D_);
    const float* prow1 = emb_e + (size_t)(n0 + w * 2 + 1) * (2 * D_);
    float2 lp00 = *(const float2*)(prow0 + 2 * l);
    float2 lp01 = *(const float2*)(prow0 + 128 + 2 * l);
    float2 lp10 = *(const float2*)(prow1 + 2 * l);
    float2 lp11 = *(const float2*)(prow1 + 128 + 2 * l);

    // ---- A-frag loads from ws (L2-hot) -------------------------------------
    const short* At = term ? A2w : A1w;
    short8 a00 = *(const short8*)(At + fr * 256 + dbase + hi * 8);
    short8 a01 = *(const short8*)(At + fr * 256 + dbase + 32 + hi * 8);
    short8 a10 = *(const short8*)(At + (16 + fr) * 256 + dbase + hi * 8);
    short8 a11 = *(const short8*)(At + (16 + fr) * 256 + dbase + 32 + hi * 8);

    // ---- stage Pb: sin/cos of scaled phase, packed bf16 --------------------
    {
        float s, c; unsigned u0, u1;
        s = sinrev_(lp00.x * K2S); c = cosrev_(lp00.x * K2S);
        u0 = ((unsigned)bf16r(c) << 16) | (unsigned)bf16r(s);
        s = sinrev_(lp00.y * K2S); c = cosrev_(lp00.y * K2S);
        u1 = ((unsigned)bf16r(c) << 16) | (unsigned)bf16r(s);
        *(uint2*)(&Pb[(w * 2) * 256 + 2 * l]) = make_uint2(u0, u1);
        s = sinrev_(lp01.x * K2S); c = cosrev_(lp01.x * K2S);
        u0 = ((unsigned)bf16r(c) << 16) | (unsigned)bf16r(s);
        s = sinrev_(lp01.y * K2S); c = cosrev_(lp01.y * K2S);
        u1 = ((unsigned)bf16r(c) << 16) | (unsigned)bf16r(s);
        *(uint2*)(&Pb[(w * 2) * 256 + 128 + 2 * l]) = make_uint2(u0, u1);
        s = sinrev_(lp10.x * K2S); c = cosrev_(lp10.x * K2S);
        u0 = ((unsigned)bf16r(c) << 16) | (unsigned)bf16r(s);
        s = sinrev_(lp10.y * K2S); c = cosrev_(lp10.y * K2S);
        u1 = ((unsigned)bf16r(c) << 16) | (unsigned)bf16r(s);
        *(uint2*)(&Pb[(w * 2 + 1) * 256 + 2 * l]) = make_uint2(u0, u1);
        s = sinrev_(lp11.x * K2S); c = cosrev_(lp11.x * K2S);
        u0 = ((unsigned)bf16r(c) << 16) | (unsigned)bf16r(s);
        s = sinrev_(lp11.y * K2S); c = cosrev_(lp11.y * K2S);
        u1 = ((unsigned)bf16r(c) << 16) | (unsigned)bf16r(s);
        *(uint2*)(&Pb[(w * 2 + 1) * 256 + 128 + 2 * l]) = make_uint2(u0, u1);
    }

    // ---- r-term MFMAs (A from ws, B packed from mt loads) ------------------
    {
        short8 bf0 = pack8(bva0, bvb0, term == 0);
        short8 bf1 = pack8(bva1, bvb1, term == 0);
        f32x4 acc0 = {0.f, 0.f, 0.f, 0.f};
        f32x4 acc1 = {0.f, 0.f, 0.f, 0.f};
        acc0 = __builtin_amdgcn_mfma_f32_16x16x32_bf16(a00, bf0, acc0, 0, 0, 0);
        acc0 = __builtin_amdgcn_mfma_f32_16x16x32_bf16(a01, bf1, acc0, 0, 0, 0);
        acc1 = __builtin_amdgcn_mfma_f32_16x16x32_bf16(a10, bf0, acc1, 0, 0, 0);
        acc1 = __builtin_amdgcn_mfma_f32_16x16x32_bf16(a11, bf1, acc1, 0, 0, 0);
        // C/D map (verified): col = lane&15 (n), row = hi*4 + reg (b)
#pragma unroll
        for (int r = 0; r < 4; ++r) {
            U[(w * 32 + hi * 4 + r) * 17 + fr]      = acc0[r];
            U[(w * 32 + 16 + hi * 4 + r) * 17 + fr] = acc1[r];
        }
    }
    __syncthreads();                                    // b1

    // ---- r reduce: thread t -> (b = t&31, n = t>>5) ------------------------
    const int fn = t >> 5, fb = t & 31;
    float rr = 0.0f;
#pragma unroll
    for (int ww = 0; ww < 8; ++ww) rr += U[(ww * 32 + fb) * 17 + fn];

    // ---- sa/ca packed loads (L2-hot) ---------------------------------------
    unsigned scp[16];
    {
        uint4 s0 = *(const uint4*)(SCw + b * 256 + d0);
        uint4 s1 = *(const uint4*)(SCw + b * 256 + d0 + 4);
        uint4 s2 = *(const uint4*)(SCw + b * 256 + d0 + 8);
        uint4 s3 = *(const uint4*)(SCw + b * 256 + d0 + 12);
        scp[0] = s0.x; scp[1] = s0.y; scp[2]  = s0.z; scp[3]  = s0.w;
        scp[4] = s1.x; scp[5] = s1.y; scp[6]  = s1.z; scp[7]  = s1.w;
        scp[8] = s2.x; scp[9] = s2.y; scp[10] = s2.z; scp[11] = s2.w;
        scp[12] = s3.x; scp[13] = s3.y; scp[14] = s3.z; scp[15] = s3.w;
    }

    // ---- phase accumulate: 16 d x 16 n; 1 b128 read = 4 triples ------------
    float sph[NT];
#pragma unroll
    for (int j = 0; j < NT; ++j) sph[j] = 0.0f;

#pragma unroll
    for (int q = 0; q < 4; ++q) {
        float saq0 = asf_(scp[q * 4 + 0] << 16), caq0 = asf_(scp[q * 4 + 0] & 0xFFFF0000u);
        float saq1 = asf_(scp[q * 4 + 1] << 16), caq1 = asf_(scp[q * 4 + 1] & 0xFFFF0000u);
        float saq2 = asf_(scp[q * 4 + 2] << 16), caq2 = asf_(scp[q * 4 + 2] & 0xFFFF0000u);
        float saq3 = asf_(scp[q * 4 + 3] << 16), caq3 = asf_(scp[q * 4 + 3] & 0xFFFF0000u);
#pragma unroll
        for (int j = 0; j < NT; ++j) {
            uint4 tv = *(const uint4*)(&Pb[j * 256 + d0 + q * 4]);   // bcast in 32-grp
            float sb, cb, sv;
            sb = asf_(tv.x << 16); cb = asf_(tv.x & 0xFFFF0000u);
            sv = fmaf(saq0, cb, -(caq0 * sb)); sph[j] += fabsf(sv);
            sb = asf_(tv.y << 16); cb = asf_(tv.y & 0xFFFF0000u);
            sv = fmaf(saq1, cb, -(caq1 * sb)); sph[j] += fabsf(sv);
            sb = asf_(tv.z << 16); cb = asf_(tv.z & 0xFFFF0000u);
            sv = fmaf(saq2, cb, -(caq2 * sb)); sph[j] += fabsf(sv);
            sb = asf_(tv.w << 16); cb = asf_(tv.w & 0xFFFF0000u);
            sv = fmaf(saq3, cb, -(caq3 * sb)); sph[j] += fabsf(sv);
        }
    }

    // ---- phase reduce ------------------------------------------------------
#pragma unroll
    for (int j = 0; j < NT; ++j) sph[j] += __shfl_xor(sph[j], 32, 64);
    __syncthreads();                                    // b2: redr consumed
    if (l < 32) {
#pragma unroll
        for (int j = 0; j < NT; ++j) U[(w * 16 + j) * 32 + l] = sph[j];
    }
    __syncthreads();                                    // b3: redf ready

    // ---- finalize: thread t -> (b = fb, n = n0 + fn) -----------------------
    {
        float pa = 0.0f;
#pragma unroll
        for (int ww = 0; ww < 8; ++ww) pa += U[(ww * 16 + fn) * 32 + fb];
        float rfull = fmaxf(rr + S0w[fb], 0.0f);
        float z = fmaf(pa, pw_p[0], sqrtf(rfull) * mw_p[0]) - 12.0f;  // GAMMA
        out[(size_t)fb * N_ + (n0 + fn)] = 1.0f / (1.0f + __expf(z));
    }
}

extern "C" void kernel_launch(void* const* d_in, const int* in_sizes, int n_in,
                              void* d_out, int out_size, void* d_ws, size_t ws_size,
                              hipStream_t stream)
{
    // inputs: 0:g 1:e1 2:rel 3:e2_multi(unused) 4:emb_e 5:emb_rel 6:phase_w 7:mod_w
    const int*   e1      = (const int*)d_in[1];
    const int*   rel     = (const int*)d_in[2];
    const float* emb_e   = (const float*)d_in[4];
    const float* emb_rel = (const float*)d_in[5];
    const float* pw      = (const float*)d_in[6];
    const float* mw      = (const float*)d_in[7];
    float* out = (float*)d_out;

    hipLaunchKernelGGL(hake_prep, dim3(32), dim3(256), 0, stream,
                       e1, rel, emb_e, emb_rel, (char*)d_ws);
    hipLaunchKernelGGL(hake_main, dim3(NBLK), dim3(512), 0, stream,
                       emb_e, (const char*)d_ws, pw, mw, out);
}